// Round 2
// baseline (949.446 us; speedup 1.0000x reference)
//
#include <hip/hip_runtime.h>

// Fused windowed multi-head attention for MI355X (gfx950).
// B=8192 windows, N=49 tokens, C=192, H=6 heads, HD=32.
// Inputs/outputs are FP32 (per reference); mask int32. Interior compute bf16 MFMA.
//
// Structure: 1 block per window, 6 waves (one per head).
//   phase 1: stage x fp32 -> bf16 (49x192 -> 64x200 padded) + mask bias in LDS
//   phase 2: QKV GEMM  (per wave: 96 cols = q|k|v of its head), mfma 16x16x32 bf16
//   phase 3: q,k row-major + v^T to per-head LDS buffers
//   phase 4: S = Q K^T (single K-step), masked softmax in registers (shfl_xor)
//   phase 5: O = P V   (P round-trips LDS in A-layout, v^T as B operand)
//   phase 6: O tile (64x192) to LDS, cooperative projection GEMM + bias, fp32 store
//
// Weights are repacked each call (d_ws re-poisoned) fp32 -> bf16 in
// B-fragment-contiguous layout: wp[(kt*COLS + col)*32 + kk] = w[(kt*32+kk)*COLS + col]
// so each MFMA B-fragment is one 16B load (full wave reads a contiguous 1KB).

typedef __attribute__((ext_vector_type(8))) short short8;
typedef __attribute__((ext_vector_type(4))) float f32x4;

#define SCALE 0.17677669529663687f   // 32^-0.5

__device__ __forceinline__ unsigned short f2bf(float x) {
    union { float f; unsigned int i; } v; v.f = x;
    return (unsigned short)((v.i + 0x7FFFu + ((v.i >> 16) & 1u)) >> 16);
}

__global__ void repack_qkv_kernel(const float* __restrict__ w,
                                  unsigned short* __restrict__ wp) {
    int idx = blockIdx.x * 256 + threadIdx.x;
    if (idx >= 6 * 576 * 32) return;
    int kk  = idx & 31;
    int col = (idx >> 5) % 576;
    int kt  = idx / (576 * 32);
    wp[idx] = f2bf(w[(kt * 32 + kk) * 576 + col]);
}

__global__ void repack_proj_kernel(const float* __restrict__ w,
                                   unsigned short* __restrict__ wp) {
    int idx = blockIdx.x * 256 + threadIdx.x;
    if (idx >= 6 * 192 * 32) return;
    int kk  = idx & 31;
    int col = (idx >> 5) % 192;
    int kt  = idx / (192 * 32);
    wp[idx] = f2bf(w[(kt * 32 + kk) * 192 + col]);
}

__global__ __launch_bounds__(384)
void win_attn_kernel(const float* __restrict__ x,
                     const int* __restrict__ mask,
                     const float* __restrict__ bqkv,
                     const float* __restrict__ bproj,
                     const unsigned short* __restrict__ wq,
                     const unsigned short* __restrict__ wpj,
                     float* __restrict__ out) {
    // region unions: [phase1-2] x tile 64x200 (12800)  [phase3-5] per-head
    // bufs q[64][40] k[64][40] vt[32][72] (7424/head * 6 = 44544), p overlays q+k
    // [phase6] O_all 64x200 (12800)
    __shared__ __align__(16) unsigned short region[44544];
    __shared__ float mbias[64];

    const int b    = blockIdx.x;
    const int tid  = threadIdx.x;
    const int lane = tid & 63;
    const int h    = tid >> 6;      // wave index == head
    const int quad = lane >> 4;
    const int l16  = lane & 15;

    // ---------------- phase 1: stage x (fp32 -> bf16), pad, mask bias -----
    const float* xb = x + (size_t)b * 9408;
    for (int i4 = tid; i4 < 2352; i4 += 384) {   // 9408 elems / 4
        int flat = i4 * 4;
        int n = flat / 192, c = flat % 192;      // 192 % 4 == 0: no row cross
        float4 v = *(const float4*)(const void*)&xb[flat];
        ushort4 pk = make_ushort4(f2bf(v.x), f2bf(v.y), f2bf(v.z), f2bf(v.w));
        *(ushort4*)(void*)&region[n * 200 + c] = pk;
    }
    if (tid < 375) {                              // zero rows 49..63 (15*200)
        uint4 z = {0u, 0u, 0u, 0u};
        *(uint4*)(void*)&region[9800 + tid * 8] = z;
    }
    if (tid < 64)
        mbias[tid] = (tid < 49 && mask[b * 49 + tid] != 0) ? 0.0f : -1e30f;
    __syncthreads();

    // ---------------- phase 2: QKV GEMM --------------------------------
    f32x4 acc[6][4];
    #pragma unroll
    for (int t = 0; t < 6; ++t)
        #pragma unroll
        for (int mt = 0; mt < 4; ++mt)
            acc[t][mt] = (f32x4){0.f, 0.f, 0.f, 0.f};

    int colb[6];
    #pragma unroll
    for (int t = 0; t < 6; ++t) colb[t] = (t >> 1) * 192 + h * 32 + (t & 1) * 16;

    #pragma unroll
    for (int kt = 0; kt < 6; ++kt) {
        short8 af[4];
        #pragma unroll
        for (int mt = 0; mt < 4; ++mt)
            af[mt] = *(const short8*)(const void*)
                     &region[(mt * 16 + l16) * 200 + kt * 32 + quad * 8];
        #pragma unroll
        for (int t = 0; t < 6; ++t) {
            short8 bw = *(const short8*)(const void*)
                        &wq[(size_t)(kt * 576 + colb[t] + l16) * 32 + quad * 8];
            #pragma unroll
            for (int mt = 0; mt < 4; ++mt)
                acc[t][mt] = __builtin_amdgcn_mfma_f32_16x16x32_bf16(
                                 af[mt], bw, acc[t][mt], 0, 0, 0);
        }
    }
    #pragma unroll
    for (int t = 0; t < 6; ++t) {
        float bv = bqkv[colb[t] + l16];
        #pragma unroll
        for (int mt = 0; mt < 4; ++mt)
            #pragma unroll
            for (int r = 0; r < 4; ++r)
                acc[t][mt][r] += bv;
    }
    __syncthreads();   // all waves done reading x; region becomes head bufs

    // ---------------- phase 3: q,k row-major; v transposed ---------------
    unsigned short* qb  = &region[h * 7424];
    unsigned short* kb  = qb + 2560;   // 64*40
    unsigned short* vtb = qb + 5120;   // vt[32][72]
    #pragma unroll
    for (int t = 0; t < 2; ++t)
        #pragma unroll
        for (int mt = 0; mt < 4; ++mt)
            #pragma unroll
            for (int r = 0; r < 4; ++r) {
                int row = mt * 16 + quad * 4 + r;
                qb[row * 40 + t * 16 + l16] = f2bf(acc[t    ][mt][r]);
                kb[row * 40 + t * 16 + l16] = f2bf(acc[t + 2][mt][r]);
            }
    #pragma unroll
    for (int t = 0; t < 2; ++t)
        #pragma unroll
        for (int mt = 0; mt < 4; ++mt) {
            int d = t * 16 + l16;
            ushort4 pk = make_ushort4(f2bf(acc[4 + t][mt][0]), f2bf(acc[4 + t][mt][1]),
                                      f2bf(acc[4 + t][mt][2]), f2bf(acc[4 + t][mt][3]));
            *(ushort4*)(void*)&vtb[d * 72 + mt * 16 + quad * 4] = pk;
        }
    // wave-local buffers; LDS ops within a wave are in-order -> no barrier

    // ---------------- phase 4: S = Q K^T, masked softmax -----------------
    f32x4 s[4][4];
    #pragma unroll
    for (int mt = 0; mt < 4; ++mt)
        #pragma unroll
        for (int nt = 0; nt < 4; ++nt)
            s[mt][nt] = (f32x4){0.f, 0.f, 0.f, 0.f};

    {
        short8 aq[4], bk[4];
        #pragma unroll
        for (int mt = 0; mt < 4; ++mt)
            aq[mt] = *(const short8*)(const void*)&qb[(mt * 16 + l16) * 40 + quad * 8];
        #pragma unroll
        for (int nt = 0; nt < 4; ++nt)
            bk[nt] = *(const short8*)(const void*)&kb[(nt * 16 + l16) * 40 + quad * 8];
        #pragma unroll
        for (int mt = 0; mt < 4; ++mt)
            #pragma unroll
            for (int nt = 0; nt < 4; ++nt)
                s[mt][nt] = __builtin_amdgcn_mfma_f32_16x16x32_bf16(
                                aq[mt], bk[nt], s[mt][nt], 0, 0, 0);
    }

    float mb[4];
    #pragma unroll
    for (int nt = 0; nt < 4; ++nt) mb[nt] = mbias[nt * 16 + l16];

    #pragma unroll
    for (int mt = 0; mt < 4; ++mt) {
        #pragma unroll
        for (int r = 0; r < 4; ++r) {
            float v0 = s[mt][0][r] * SCALE + mb[0];
            float v1 = s[mt][1][r] * SCALE + mb[1];
            float v2 = s[mt][2][r] * SCALE + mb[2];
            float v3 = s[mt][3][r] * SCALE + mb[3];
            float mx = fmaxf(fmaxf(v0, v1), fmaxf(v2, v3));
            mx = fmaxf(mx, __shfl_xor(mx, 1));
            mx = fmaxf(mx, __shfl_xor(mx, 2));
            mx = fmaxf(mx, __shfl_xor(mx, 4));
            mx = fmaxf(mx, __shfl_xor(mx, 8));
            float e0 = __expf(v0 - mx), e1 = __expf(v1 - mx);
            float e2 = __expf(v2 - mx), e3 = __expf(v3 - mx);
            float sum = e0 + e1 + e2 + e3;
            sum += __shfl_xor(sum, 1);
            sum += __shfl_xor(sum, 2);
            sum += __shfl_xor(sum, 4);
            sum += __shfl_xor(sum, 8);
            float inv = 1.0f / sum;
            s[mt][0][r] = e0 * inv; s[mt][1][r] = e1 * inv;
            s[mt][2][r] = e2 * inv; s[mt][3][r] = e3 * inv;
        }
    }

    // P -> LDS in A-layout (overlays q and part of k; k reads already done)
    unsigned short* pb = qb;   // p[64][72]: 4608 <= 5120 (q+k)
    #pragma unroll
    for (int mt = 0; mt < 4; ++mt)
        #pragma unroll
        for (int nt = 0; nt < 4; ++nt)
            #pragma unroll
            for (int r = 0; r < 4; ++r)
                pb[(mt * 16 + quad * 4 + r) * 72 + nt * 16 + l16] = f2bf(s[mt][nt][r]);

    // ---------------- phase 5: O = P V -----------------------------------
    f32x4 o[4][2];
    #pragma unroll
    for (int mt = 0; mt < 4; ++mt)
        #pragma unroll
        for (int dt = 0; dt < 2; ++dt)
            o[mt][dt] = (f32x4){0.f, 0.f, 0.f, 0.f};

    #pragma unroll
    for (int kt = 0; kt < 2; ++kt) {
        short8 ap[4], bv[2];
        #pragma unroll
        for (int mt = 0; mt < 4; ++mt)
            ap[mt] = *(const short8*)(const void*)
                     &pb[(mt * 16 + l16) * 72 + kt * 32 + quad * 8];
        #pragma unroll
        for (int dt = 0; dt < 2; ++dt)
            bv[dt] = *(const short8*)(const void*)
                     &vtb[(dt * 16 + l16) * 72 + kt * 32 + quad * 8];
        #pragma unroll
        for (int mt = 0; mt < 4; ++mt)
            #pragma unroll
            for (int dt = 0; dt < 2; ++dt)
                o[mt][dt] = __builtin_amdgcn_mfma_f32_16x16x32_bf16(
                                ap[mt], bv[dt], o[mt][dt], 0, 0, 0);
    }

    __syncthreads();   // all waves done with attn bufs; region becomes O_all
    #pragma unroll
    for (int dt = 0; dt < 2; ++dt)
        #pragma unroll
        for (int mt = 0; mt < 4; ++mt)
            #pragma unroll
            for (int r = 0; r < 4; ++r)
                region[(mt * 16 + quad * 4 + r) * 200 + h * 32 + dt * 16 + l16]
                    = f2bf(o[mt][dt][r]);
    __syncthreads();

    // ---------------- phase 6: projection GEMM + bias + fp32 store -------
    f32x4 po[2][4];
    #pragma unroll
    for (int nt = 0; nt < 2; ++nt)
        #pragma unroll
        for (int mt = 0; mt < 4; ++mt)
            po[nt][mt] = (f32x4){0.f, 0.f, 0.f, 0.f};

    #pragma unroll
    for (int kt = 0; kt < 6; ++kt) {
        short8 ao[4];
        #pragma unroll
        for (int mt = 0; mt < 4; ++mt)
            ao[mt] = *(const short8*)(const void*)
                     &region[(mt * 16 + l16) * 200 + kt * 32 + quad * 8];
        #pragma unroll
        for (int nt = 0; nt < 2; ++nt) {
            int col = h * 32 + nt * 16 + l16;
            short8 bw = *(const short8*)(const void*)
                        &wpj[(size_t)(kt * 192 + col) * 32 + quad * 8];
            #pragma unroll
            for (int mt = 0; mt < 4; ++mt)
                po[nt][mt] = __builtin_amdgcn_mfma_f32_16x16x32_bf16(
                                 ao[mt], bw, po[nt][mt], 0, 0, 0);
        }
    }

    #pragma unroll
    for (int nt = 0; nt < 2; ++nt) {
        int col = h * 32 + nt * 16 + l16;
        float bv = bproj[col];
        #pragma unroll
        for (int mt = 0; mt < 4; ++mt)
            #pragma unroll
            for (int r = 0; r < 4; ++r) {
                int row = mt * 16 + quad * 4 + r;
                if (row < 49)
                    out[(size_t)b * 9408 + row * 192 + col] = po[nt][mt][r] + bv;
            }
    }
}

extern "C" void kernel_launch(void* const* d_in, const int* in_sizes, int n_in,
                              void* d_out, int out_size, void* d_ws, size_t ws_size,
                              hipStream_t stream) {
    const float* x      = (const float*)d_in[0];
    const int*   mask   = (const int*)d_in[1];
    const float* w_qkv  = (const float*)d_in[2];
    const float* b_qkv  = (const float*)d_in[3];
    const float* w_proj = (const float*)d_in[4];
    const float* b_proj = (const float*)d_in[5];
    float*       out    = (float*)d_out;

    unsigned short* wq_pack = (unsigned short*)d_ws;          // 110592 elems
    unsigned short* wp_pack = wq_pack + 110592;               //  36864 elems

    repack_qkv_kernel <<<(110592 + 255) / 256, 256, 0, stream>>>(w_qkv,  wq_pack);
    repack_proj_kernel<<<( 36864 + 255) / 256, 256, 0, stream>>>(w_proj, wp_pack);
    win_attn_kernel<<<8192, 384, 0, stream>>>(x, mask, b_qkv, b_proj,
                                              wq_pack, wp_pack, out);
}